// Round 23
// baseline (9918.546 us; speedup 1.0000x reference)
//
#include <hip/hip_runtime.h>

// DownSampling: B=16, N=16384, C=128, M=4096. f32 in/out.
// LOCKED ORACLE SEMANTICS (R14, absmax==0): per point,
//   dx=px-cx; dy=py-cy; dz=pz-cz;
//   d = fma(dz,dz, fma(dx,dx, rn(dy*dy)))   [XLA-GPU tree contraction]
//   dist = min(dist, d); argmax = (max value, MIN original index).
// R23 redesign: TPB=256, PPT=64 (1 wave/SIMD, ~280 VGPR) -> barriers sync
// 4 waves not 16; block reduce = 1 ds_read_b128 + 2 max ops. Winner posts
// (idx<<32|coordbits) via 3 u64 LDS atomicMin (min-idx tie-break exact) so
// the next centroid is a broadcast LDS read — no j-dependent fetch, no
// coord cache. Scalar f32 distance phase (v_pk_f32 is zero-gain: R15/16/22).
#define B_   16
#define N_   16384
#define C_   128
#define M_   4096
#define TPB  256
#define PPT  64    // points per thread: TPB*PPT == N_

typedef unsigned long long u64;
typedef unsigned int u32;

#define DPP_QUAD_XOR1   0xB1   // quad_perm [1,0,3,2]
#define DPP_QUAD_XOR2   0x4E   // quad_perm [2,3,0,1]
#define DPP_HALF_MIRROR 0x141  // mirror within 8-lane half-rows
#define DPP_ROW_MIRROR  0x140  // mirror within 16-lane rows
#define DPP_BCAST15     0x142  // lane15 -> 16..31, lane47 -> 48..63
#define DPP_BCAST31     0x143  // lane31 -> 32..63

// max-join with DPP-permuted partner (update_dpp: unwritten lanes keep old)
#define VMAX_DPP(V, CTRL) do{                                                      \
    float _o = __int_as_float(__builtin_amdgcn_update_dpp(                         \
        __float_as_int(V), __float_as_int(V), (CTRL), 0xF, 0xF, false));           \
    (V) = fmaxf((V), _o);                                                          \
}while(0)

// static descending scan of group G (16 points): first (lowest jj) match wins
#define SCAN16(G) do{                                                              \
    _Pragma("unroll")                                                              \
    for (int s = 15; s >= 0; --s) {                                                \
        const int jj = (G) * 16 + s;                                               \
        const bool h = (dd[jj] == bmax);                                           \
        wi = h ? (1024 * (jj >> 2) + 4 * t + (jj & 3)) : wi;                       \
        wx = h ? px[jj] : wx;                                                      \
        wy = h ? py[jj] : wy;                                                      \
        wz = h ? pz[jj] : wz;                                                      \
    }                                                                              \
}while(0)

__global__ __launch_bounds__(TPB, 1) void fps_kernel(const float* __restrict__ xyz,
                                                     int* __restrict__ idx_out)
{
    const int b = blockIdx.x;
    const int t = threadIdx.x;
    const int wid  = t >> 6;
    const int lane = t & 63;
    const float* xb = xyz + (size_t)b * 3 * N_;

    float px[PPT], py[PPT], pz[PPT], dd[PPT];

    // Thread t owns points {1024*i + 4*t + k : i in [0,16), k in [0,4)} —
    // float4 loads are fully coalesced (consecutive lanes, consecutive 16B).
    {
        const float4* x4 = reinterpret_cast<const float4*>(xb);
        const float4* y4 = reinterpret_cast<const float4*>(xb + N_);
        const float4* z4 = reinterpret_cast<const float4*>(xb + 2 * N_);
        #pragma unroll
        for (int i = 0; i < 16; ++i) {
            float4 vx = x4[i * 256 + t];
            float4 vy = y4[i * 256 + t];
            float4 vz = z4[i * 256 + t];
            px[i*4+0] = vx.x; px[i*4+1] = vx.y; px[i*4+2] = vx.z; px[i*4+3] = vx.w;
            py[i*4+0] = vy.x; py[i*4+1] = vy.y; py[i*4+2] = vy.z; py[i*4+3] = vy.w;
            pz[i*4+0] = vz.x; pz[i*4+1] = vz.y; pz[i*4+2] = vz.z; pz[i*4+3] = vz.w;
        }
    }
    #pragma unroll
    for (int i = 0; i < PPT; ++i) dd[i] = 1e10f;   // BIG sentinel

    __shared__ float4 lvv[4];      // per-wave value partials (4-ring of float4)
    __shared__ u64    cring[4][3]; // (origIdx<<32)|coordbits rings (atomicMin)

    if (t < 12) ((u64*)cring)[t] = ~0ull;   // init rings to MAX
    if (t == 0) idx_out[b * M_ + 0] = 0;    // deterministic start at index 0

    __syncthreads();   // order ring init before first iteration

    // First centroid = point 0.
    float cx = xb[0], cy = xb[N_], cz = xb[2 * N_];

    for (int m = 1; m < M_; ++m) {
        const int buf = m & 3;

        // ---- a: distance update (locked semantics); 4 group maxes (16 pts each)
        float g0 = -1.0f, g1 = -1.0f, g2 = -1.0f, g3 = -1.0f;
        #pragma unroll
        for (int p = 0; p < PPT / 2; ++p) {     // pairs 2p, 2p+1
            const int i0 = 2 * p, i1 = 2 * p + 1;
            float dx0 = __fsub_rn(px[i0], cx);
            float dy0 = __fsub_rn(py[i0], cy);
            float dz0 = __fsub_rn(pz[i0], cz);
            float d0  = fmaf(dz0, dz0, fmaf(dx0, dx0, __fmul_rn(dy0, dy0)));
            float n0  = fminf(dd[i0], d0);
            dd[i0] = n0;
            float dx1 = __fsub_rn(px[i1], cx);
            float dy1 = __fsub_rn(py[i1], cy);
            float dz1 = __fsub_rn(pz[i1], cz);
            float d1  = fmaf(dz1, dz1, fmaf(dx1, dx1, __fmul_rn(dy1, dy1)));
            float n1  = fminf(dd[i1], d1);
            dd[i1] = n1;
            if      (p <  8) g0 = fmaxf(fmaxf(g0, n0), n1);   // v_max3_f32
            else if (p < 16) g1 = fmaxf(fmaxf(g1, n0), n1);
            else if (p < 24) g2 = fmaxf(fmaxf(g2, n0), n1);
            else             g3 = fmaxf(fmaxf(g3, n0), n1);
        }
        const float lmax = fmaxf(fmaxf(g0, g1), fmaxf(g2, g3));

        // ---- b: all-DPP wave value-reduce; lane 63 ends with the wave max
        float vmax = lmax;
        VMAX_DPP(vmax, DPP_QUAD_XOR1);
        VMAX_DPP(vmax, DPP_QUAD_XOR2);
        VMAX_DPP(vmax, DPP_HALF_MIRROR);
        VMAX_DPP(vmax, DPP_ROW_MIRROR);
        VMAX_DPP(vmax, DPP_BCAST15);
        VMAX_DPP(vmax, DPP_BCAST31);
        if (lane == 63) ((float*)&lvv[buf])[wid] = vmax;
        __syncthreads();   // B1

        // ---- c: block max from 4 partials (one b128 broadcast read + 2 ops)
        const float4 lw = lvv[buf];
        const float bmax = fmaxf(fmaxf(lw.x, lw.y), fmaxf(lw.z, lw.w));

        // ---- d: rare winner posts (origIdx, coords) via 3 u64 atomicMin
        if (lmax == bmax) {
            int wi = 0x7fffffff;
            float wx = 0.0f, wy = 0.0f, wz = 0.0f;
            if      (g0 == bmax) { SCAN16(0); }
            else if (g1 == bmax) { SCAN16(1); }
            else if (g2 == bmax) { SCAN16(2); }
            else                 { SCAN16(3); }
            const u64 hi = ((u64)(u32)wi) << 32;
            atomicMin(&cring[buf][0], hi | (u64)__float_as_uint(wx));
            atomicMin(&cring[buf][1], hi | (u64)__float_as_uint(wy));
            atomicMin(&cring[buf][2], hi | (u64)__float_as_uint(wz));
        }
        __syncthreads();   // B2

        // ---- e: broadcast winner coords + index; reset ring slot m+2
        const u64 kx = cring[buf][0];
        const u64 ky = cring[buf][1];
        const u64 kz = cring[buf][2];
        cx = __uint_as_float((u32)kx);
        cy = __uint_as_float((u32)ky);
        cz = __uint_as_float((u32)kz);
        if (t == 0) idx_out[b * M_ + m] = (int)(kx >> 32);
        if (t < 3) cring[(m + 2) & 3][t] = ~0ull;
    }
}

// -------------------------------------------------------------------------
// Gather kernel: one block per (batch, output row). Rows 0..2 = xyz, 3..130 =
// feature channels. Raw f32 passthrough of gathered values.
// -------------------------------------------------------------------------
__global__ void gather_kernel(const float* __restrict__ xyz,
                              const float* __restrict__ feat,
                              const int*   __restrict__ idx,
                              float*       __restrict__ out)
{
    const int blk = blockIdx.x;
    const int b = blk / (3 + C_);
    const int r = blk % (3 + C_);
    const int* idb = idx + b * M_;

    if (r < 3) {
        const float* src = xyz + ((size_t)b * 3 + r) * N_;
        float*       dst = out + ((size_t)b * 3 + r) * M_;
        for (int m = threadIdx.x; m < M_; m += blockDim.x)
            dst[m] = src[idb[m]];
    } else {
        const int c = r - 3;
        const float* src = feat + ((size_t)b * C_ + c) * N_;
        float*       dst = out + (size_t)B_ * 3 * M_ + ((size_t)b * C_ + c) * M_;
        for (int m = threadIdx.x; m < M_; m += blockDim.x)
            dst[m] = src[idb[m]];
    }
}

extern "C" void kernel_launch(void* const* d_in, const int* in_sizes, int n_in,
                              void* d_out, int out_size, void* d_ws, size_t ws_size,
                              hipStream_t stream)
{
    const float* xyz  = (const float*)d_in[0];   // [16, 3, 16384] f32
    const float* feat = (const float*)d_in[1];   // [16, 128, 16384] f32
    float* out = (float*)d_out;                  // [16*3*4096] + [16*128*4096] f32
    int*   idx = (int*)d_ws;                     // [16, 4096] int32 scratch

    fps_kernel<<<dim3(B_), dim3(TPB), 0, stream>>>(xyz, idx);
    gather_kernel<<<dim3(B_ * (3 + C_)), dim3(256), 0, stream>>>(xyz, feat, idx, out);
}

// Round 24
// 5346.948 us; speedup vs baseline: 1.8550x; 1.8550x over previous
//
#include <hip/hip_runtime.h>

// DownSampling: B=16, N=16384, C=128, M=4096. f32 in/out.
// LOCKED ORACLE SEMANTICS (R14, absmax==0): per point,
//   dx=px-cx; dy=py-cy; dz=pz-cz;
//   d = fma(dz,dz, fma(dx,dx, rn(dy*dy)))   [XLA-GPU tree contraction]
//   dist = min(dist, d); argmax = (max value, MIN index).
// R24 = R19 + LOAD LAUNDERING. R23's spill exposed that VGPR_Count=44 in
// R14-R22 cannot hold the 64-float state: the compiler REMATERIALIZES
// px/py/pz from global (L2) every iteration (~192KB/CU/iter ~ 3200cyc of
// covert L2 traffic = the real floor). Fix: pass each loaded coord through
// a ONE-TIME empty asm ("+v") before the loop — asm results are opaque and
// cannot be rematerialized, forcing true register residency (state+temps
// ~108 < 128 VGPR cap @ 4 waves/SIMD). Everything else is R19 verbatim.
#define B_   16
#define N_   16384
#define C_   128
#define M_   4096
#define TPB  1024
#define PPT  16    // points per thread: TPB*PPT == N_
#define NC   10880 // points with coords cached in LDS (3*NC*4 = 130560 B)

#define DPP_QUAD_XOR1   0xB1   // quad_perm [1,0,3,2]
#define DPP_QUAD_XOR2   0x4E   // quad_perm [2,3,0,1]
#define DPP_HALF_MIRROR 0x141  // mirror within 8-lane half-rows
#define DPP_ROW_MIRROR  0x140  // mirror within 16-lane rows
#define SWZ_XOR16       0x401F // BitMode xor-16 within 32-lane groups

// value-only max join via DPP (VALU pipe) — R19-proven
#define VMAX_DPP(V, CTRL) do{                                                      \
    float _o = __int_as_float(__builtin_amdgcn_mov_dpp(__float_as_int(V),          \
                                                       (CTRL), 0xF, 0xF, 0));      \
    (V) = fmaxf((V), _o);                                                          \
}while(0)

// value-only max join via ds_swizzle xor pattern — R19-proven
#define VMAX_SWZ(V, PAT) do{                                                       \
    float _o = __int_as_float(__builtin_amdgcn_ds_swizzle(__float_as_int(V), PAT));\
    (V) = fmaxf((V), _o);                                                          \
}while(0)

// one-time load laundering: makes the 4 values asm-defined (non-remat-able)
#define LAUNDER4(A,Bv,Cv,Dv) asm("" : "+v"(A), "+v"(Bv), "+v"(Cv), "+v"(Dv))

__global__ __launch_bounds__(TPB, 4) void fps_kernel(const float* __restrict__ xyz,
                                                     int* __restrict__ idx_out)
{
    const int b = blockIdx.x;
    const int t = threadIdx.x;
    const int wid  = t >> 6;
    const int lane = t & 63;
    const float* xb = xyz + (size_t)b * 3 * N_;

    extern __shared__ float smem[];          // dynamic: coord cache
    float* cX = smem;
    float* cY = smem + NC;
    float* cZ = smem + 2 * NC;

    float px[PPT], py[PPT], pz[PPT], dist[PPT];

    // Load 16 consecutive points per thread (float4-vectorized, coalesced).
    {
        const float4* x4 = reinterpret_cast<const float4*>(xb);
        const float4* y4 = reinterpret_cast<const float4*>(xb + N_);
        const float4* z4 = reinterpret_cast<const float4*>(xb + 2 * N_);
        #pragma unroll
        for (int q = 0; q < 4; ++q) {
            float4 vx = x4[t * 4 + q];
            float4 vy = y4[t * 4 + q];
            float4 vz = z4[t * 4 + q];
            px[q*4+0] = vx.x; px[q*4+1] = vx.y; px[q*4+2] = vx.z; px[q*4+3] = vx.w;
            py[q*4+0] = vy.x; py[q*4+1] = vy.y; py[q*4+2] = vy.z; py[q*4+3] = vy.w;
            pz[q*4+0] = vz.x; pz[q*4+1] = vz.y; pz[q*4+2] = vz.z; pz[q*4+3] = vz.w;
        }
    }
    // LAUNDER: one-time, before the loop. Values become asm-defined ->
    // the compiler cannot reload them from global inside the loop.
    #pragma unroll
    for (int q = 0; q < 4; ++q) {
        LAUNDER4(px[q*4+0], px[q*4+1], px[q*4+2], px[q*4+3]);
        LAUNDER4(py[q*4+0], py[q*4+1], py[q*4+2], py[q*4+3]);
        LAUNDER4(pz[q*4+0], pz[q*4+1], pz[q*4+2], pz[q*4+3]);
    }

    #pragma unroll
    for (int i = 0; i < PPT; ++i) dist[i] = 1e10f;  // BIG sentinel

    // Fill LDS coord cache (one-time; visible by first use via iter-1 barriers).
    for (int p = t; p < NC; p += TPB) {
        cX[p] = xb[p];
        cY[p] = xb[N_ + p];
        cZ[p] = xb[2 * N_ + p];
    }

    __shared__ float lv[4][16];   // per-wave value partials (4-ring)
    __shared__ int   widx[4];     // winning-index word per ring

    if (t < 4) widx[t] = 0x7fffffff;   // init rings; visible after B1(m=1)

    if (t == 0) idx_out[b * M_ + 0] = 0;   // deterministic start at index 0

    // First centroid = point 0.
    float cx = xb[0], cy = xb[N_], cz = xb[2 * N_];

    for (int m = 1; m < M_; ++m) {
        const int buf = m & 3;

        // ---- a: distance update (locked semantics) + value max (max3 pairs)
        float vmax = -1.0f;
        #pragma unroll
        for (int i = 0; i < PPT; i += 2) {
            float dx0 = __fsub_rn(px[i], cx);
            float dy0 = __fsub_rn(py[i], cy);
            float dz0 = __fsub_rn(pz[i], cz);
            float d0  = fmaf(dz0, dz0, fmaf(dx0, dx0, __fmul_rn(dy0, dy0)));
            float n0  = fminf(dist[i], d0);
            dist[i] = n0;
            float dx1 = __fsub_rn(px[i+1], cx);
            float dy1 = __fsub_rn(py[i+1], cy);
            float dz1 = __fsub_rn(pz[i+1], cz);
            float d1  = fmaf(dz1, dz1, fmaf(dx1, dx1, __fmul_rn(dy1, dy1)));
            float n1  = fminf(dist[i+1], d1);
            dist[i+1] = n1;
            vmax = fmaxf(fmaxf(vmax, n0), n1);   // fuses to v_max3_f32 (exact)
        }
        const float lmax = vmax;   // pre-reduce local max for match test

        // ---- b: wave value-reduce (4 DPP + xor16 swizzle + xor32 shfl)
        VMAX_DPP(vmax, DPP_QUAD_XOR1);
        VMAX_DPP(vmax, DPP_QUAD_XOR2);
        VMAX_DPP(vmax, DPP_HALF_MIRROR);
        VMAX_DPP(vmax, DPP_ROW_MIRROR);
        VMAX_SWZ(vmax, SWZ_XOR16);
        vmax = fmaxf(vmax, __shfl_xor(vmax, 32));

        // ---- c: publish wave partial; reset ring for iter m+2 (barrier-safe)
        if (lane == 0) lv[buf][wid] = vmax;
        if (t == 0) widx[(m + 2) & 3] = 0x7fffffff;
        __syncthreads();   // B1

        // ---- d: block value-reduce (16 partials, pure DPP within 16-lane row)
        float v2 = (lane < 16) ? lv[buf][lane] : -1.0f;
        VMAX_DPP(v2, DPP_QUAD_XOR1);
        VMAX_DPP(v2, DPP_QUAD_XOR2);
        VMAX_DPP(v2, DPP_HALF_MIRROR);
        VMAX_DPP(v2, DPP_ROW_MIRROR);
        const float bmax = __int_as_float(
            __builtin_amdgcn_readfirstlane(__float_as_int(v2)));

        // ---- e: rare index-find (only matching thread(s); waves skip via execz)
        if (lmax == bmax) {
            int cand = 0;
            #pragma unroll
            for (int i = PPT - 1; i >= 0; --i)      // descending: smallest slot wins
                cand = (dist[i] == bmax) ? i : cand;
            atomicMin(&widx[buf], t * PPT + cand);  // global MIN index (tie-break)
        }
        __syncthreads();   // B2

        // ---- f: read winner, emit, reload centroid (LDS-cached or VMEM)
        const int j = __builtin_amdgcn_readfirstlane(widx[buf]);
        if (t == 0) idx_out[b * M_ + m] = j;
        if (j < NC) {   // uniform scalar branch; ds_read broadcast (~70cyc)
            cx = cX[j];
            cy = cY[j];
            cz = cZ[j];
        } else {        // fallback: L2 loads (~200cyc), 34% of iterations
            cx = xb[j];
            cy = xb[N_ + j];
            cz = xb[2 * N_ + j];
        }
    }
}

// -------------------------------------------------------------------------
// Gather kernel: one block per (batch, output row). Rows 0..2 = xyz, 3..130 =
// feature channels. Raw f32 passthrough of gathered values.
// -------------------------------------------------------------------------
__global__ void gather_kernel(const float* __restrict__ xyz,
                              const float* __restrict__ feat,
                              const int*   __restrict__ idx,
                              float*       __restrict__ out)
{
    const int blk = blockIdx.x;
    const int b = blk / (3 + C_);
    const int r = blk % (3 + C_);
    const int* idb = idx + b * M_;

    if (r < 3) {
        const float* src = xyz + ((size_t)b * 3 + r) * N_;
        float*       dst = out + ((size_t)b * 3 + r) * M_;
        for (int m = threadIdx.x; m < M_; m += blockDim.x)
            dst[m] = src[idb[m]];
    } else {
        const int c = r - 3;
        const float* src = feat + ((size_t)b * C_ + c) * N_;
        float*       dst = out + (size_t)B_ * 3 * M_ + ((size_t)b * C_ + c) * M_;
        for (int m = threadIdx.x; m < M_; m += blockDim.x)
            dst[m] = src[idb[m]];
    }
}

extern "C" void kernel_launch(void* const* d_in, const int* in_sizes, int n_in,
                              void* d_out, int out_size, void* d_ws, size_t ws_size,
                              hipStream_t stream)
{
    const float* xyz  = (const float*)d_in[0];   // [16, 3, 16384] f32
    const float* feat = (const float*)d_in[1];   // [16, 128, 16384] f32
    float* out = (float*)d_out;                  // [16*3*4096] + [16*128*4096] f32
    int*   idx = (int*)d_ws;                     // [16, 4096] int32 scratch

    const size_t dyn_lds = (size_t)3 * NC * sizeof(float);   // 130560 B
    fps_kernel<<<dim3(B_), dim3(TPB), dyn_lds, stream>>>(xyz, idx);
    gather_kernel<<<dim3(B_ * (3 + C_)), dim3(256), 0, stream>>>(xyz, feat, idx, out);
}